// Round 1
// 287.534 us; speedup vs baseline: 1.0136x; 1.0136x over previous
//
#include <hip/hip_runtime.h>

#define BT_D  512
#define BT_D4 128   // D / 4 float4 groups per row
#define NBLK  1024
#define NTHR  512   // 8 waves/block; 4 blocks/CU -> 32 waves/CU (full occupancy)
#define BT_U  2     // named-var unroll: 4 independent 16B loads in flight/wave

// Accumulate one (e,tau) float4 pair into the 5 stat accumulators.
#define BT_ACC(ev, tv)                                                  \
    do {                                                                \
        se.x += (ev).x; se.y += (ev).y; se.z += (ev).z; se.w += (ev).w; \
        st.x += (tv).x; st.y += (tv).y; st.z += (tv).z; st.w += (tv).w; \
        se2.x = fmaf((ev).x, (ev).x, se2.x);                            \
        se2.y = fmaf((ev).y, (ev).y, se2.y);                            \
        se2.z = fmaf((ev).z, (ev).z, se2.z);                            \
        se2.w = fmaf((ev).w, (ev).w, se2.w);                            \
        st2.x = fmaf((tv).x, (tv).x, st2.x);                            \
        st2.y = fmaf((tv).y, (tv).y, st2.y);                            \
        st2.z = fmaf((tv).z, (tv).z, st2.z);                            \
        st2.w = fmaf((tv).w, (tv).w, st2.w);                            \
        set.x = fmaf((ev).x, (tv).x, set.x);                            \
        set.y = fmaf((ev).y, (tv).y, set.y);                            \
        set.z = fmaf((ev).z, (tv).z, set.z);                            \
        set.w = fmaf((ev).w, (tv).w, set.w);                            \
    } while (0)

#define BT_ADD4(dst, a) \
    do { (dst).x += (a).x; (dst).y += (a).y; (dst).z += (a).z; (dst).w += (a).w; } while (0)

// Kernel 1: flat grid-stride over the N4 = B*128 float4 stream.
// R(prev) post-mortem: VALUBusy=2.6%, VGPR=36, 1.6 TB/s -> latency-bound with
// ~2 loads in flight/wave at only 16 waves/CU. Fix is TLP: 512-thr blocks at
// __launch_bounds__(512,8) -> 64-VGPR cap, 32 waves/CU resident. Unroll kept
// small (2 pairs, named vars) so the 64-VGPR budget holds without spill.
__global__ __launch_bounds__(NTHR, 8) void bt_partial_kernel(
    const float4* __restrict__ e4, const float4* __restrict__ t4,
    float* __restrict__ acc, int B, int nslot)
{
    const int tid = threadIdx.x;
    const int c4  = tid & (BT_D4 - 1);
    const int r   = tid >> 7;            // 0..3 (four 128-thread groups)

    float4 se  = make_float4(0.f, 0.f, 0.f, 0.f);
    float4 se2 = make_float4(0.f, 0.f, 0.f, 0.f);
    float4 st  = make_float4(0.f, 0.f, 0.f, 0.f);
    float4 st2 = make_float4(0.f, 0.f, 0.f, 0.f);
    float4 set = make_float4(0.f, 0.f, 0.f, 0.f);

    // 32-bit indexing: N4 = 8.39e6 fits easily; byte offsets < 2^28.
    const unsigned T  = (unsigned)gridDim.x * NTHR;
    const unsigned N4 = (unsigned)B * BT_D4;
    unsigned i = (unsigned)blockIdx.x * NTHR + tid;

    // main loop: 4 independent 16B loads issued before any use
    for (; i + T < N4; i += BT_U * T) {
        const float4 e0 = e4[i];
        const float4 t0 = t4[i];
        const float4 e1 = e4[i + T];
        const float4 t1 = t4[i + T];
        BT_ACC(e0, t0);
        BT_ACC(e1, t1);
    }
    for (; i < N4; i += T) {
        const float4 ev = e4[i];
        const float4 tv = t4[i];
        BT_ACC(ev, tv);
    }

    // LDS tree fold: r{2,3} -> r{0,1}, then r1 -> r0.  (T multiple of 128 and
    // block base multiple of 128, so thread's column group is tid&127.)
    __shared__ float4 lds[2][BT_D4][5];
    if (r >= 2) {
        float4 (*L)[5] = lds[r - 2];
        L[c4][0] = se;  L[c4][1] = se2; L[c4][2] = st;
        L[c4][3] = st2; L[c4][4] = set;
    }
    __syncthreads();
    if (r < 2) {
        float4 (*L)[5] = lds[r];
        BT_ADD4(se,  L[c4][0]); BT_ADD4(se2, L[c4][1]); BT_ADD4(st, L[c4][2]);
        BT_ADD4(st2, L[c4][3]); BT_ADD4(set, L[c4][4]);
    }
    __syncthreads();
    if (r == 1) {
        lds[0][c4][0] = se;  lds[0][c4][1] = se2; lds[0][c4][2] = st;
        lds[0][c4][3] = st2; lds[0][c4][4] = set;
    }
    __syncthreads();
    if (r == 0) {
        BT_ADD4(se,  lds[0][c4][0]); BT_ADD4(se2, lds[0][c4][1]);
        BT_ADD4(st,  lds[0][c4][2]); BT_ADD4(st2, lds[0][c4][3]);
        BT_ADD4(set, lds[0][c4][4]);

        // nslot is a power of two -> mask instead of %
        float* ap = acc + (size_t)(blockIdx.x & (nslot - 1)) * (5 * BT_D);
        const int col = c4 * 4;
        atomicAdd(&ap[0 * BT_D + col + 0], se.x);
        atomicAdd(&ap[0 * BT_D + col + 1], se.y);
        atomicAdd(&ap[0 * BT_D + col + 2], se.z);
        atomicAdd(&ap[0 * BT_D + col + 3], se.w);
        atomicAdd(&ap[1 * BT_D + col + 0], se2.x);
        atomicAdd(&ap[1 * BT_D + col + 1], se2.y);
        atomicAdd(&ap[1 * BT_D + col + 2], se2.z);
        atomicAdd(&ap[1 * BT_D + col + 3], se2.w);
        atomicAdd(&ap[2 * BT_D + col + 0], st.x);
        atomicAdd(&ap[2 * BT_D + col + 1], st.y);
        atomicAdd(&ap[2 * BT_D + col + 2], st.z);
        atomicAdd(&ap[2 * BT_D + col + 3], st.w);
        atomicAdd(&ap[3 * BT_D + col + 0], st2.x);
        atomicAdd(&ap[3 * BT_D + col + 1], st2.y);
        atomicAdd(&ap[3 * BT_D + col + 2], st2.z);
        atomicAdd(&ap[3 * BT_D + col + 3], st2.w);
        atomicAdd(&ap[4 * BT_D + col + 0], set.x);
        atomicAdd(&ap[4 * BT_D + col + 1], set.y);
        atomicAdd(&ap[4 * BT_D + col + 2], set.z);
        atomicAdd(&ap[4 * BT_D + col + 3], set.w);
    }
}

// Kernel 2: finalize per-column stats (fp64 for safety).
// R(prev): single 512-thread block = one CU doing 160 latency-bound loads per
// thread. Now 8 blocks x 64 threads (one column/thread, one wave/block) on 8
// CUs; wave shuffle-reduce; one fp32 atomicAdd into out (zeroed by memset).
__global__ __launch_bounds__(64) void bt_final_kernel(
    const float* __restrict__ acc, float* __restrict__ out, int B, int nslot)
{
    const int d = blockIdx.x * 64 + threadIdx.x;   // 8 blocks x 64 = 512 cols
    double Se = 0, Se2 = 0, St = 0, St2 = 0, Set = 0;
#pragma unroll 4
    for (int s = 0; s < nslot; ++s) {
        const float* a = acc + (size_t)s * (5 * BT_D);
        Se  += a[0 * BT_D + d];
        Se2 += a[1 * BT_D + d];
        St  += a[2 * BT_D + d];
        St2 += a[3 * BT_D + d];
        Set += a[4 * BT_D + d];
    }
    const double Bd = (double)B;
    const double me = Se / Bd, mt = St / Bd;
    double ve = (Se2 - Bd * me * me) / (Bd - 1.0);
    double vt = (St2 - Bd * mt * mt) / (Bd - 1.0);
    ve = ve > 0.0 ? ve : 0.0;
    vt = vt > 0.0 ? vt : 0.0;
    const double sd_e = sqrt(ve) + 1e-9;
    const double sd_t = sqrt(vt) + 1e-9;
    const double c = (Set - Bd * me * mt) / (sd_e * sd_t * Bd);
    double v = (1.0 - c) * (1.0 - c);

    // wave-64 shuffle reduction
    for (int off = 32; off > 0; off >>= 1)
        v += __shfl_down(v, off, 64);
    if (threadIdx.x == 0)
        atomicAdd(out, (float)v);
}

extern "C" void kernel_launch(void* const* d_in, const int* in_sizes, int n_in,
                              void* d_out, int out_size, void* d_ws, size_t ws_size,
                              hipStream_t stream) {
    const float* e   = (const float*)d_in[0];
    const float* tau = (const float*)d_in[1];
    const int B = in_sizes[0] / BT_D;
    float* acc = (float*)d_ws;

    // accumulator copies: atomic same-address chain depth = NBLK / nslot
    int nslot = 1;
    const size_t slot_bytes = (size_t)5 * BT_D * sizeof(float);
    if (ws_size >= 32 * slot_bytes)      nslot = 32;
    else if (ws_size >= 8 * slot_bytes)  nslot = 8;
    else if (ws_size >= 4 * slot_bytes)  nslot = 4;
    else if (ws_size >= 2 * slot_bytes)  nslot = 2;

    (void)hipMemsetAsync(d_ws, 0, (size_t)nslot * slot_bytes, stream);
    (void)hipMemsetAsync(d_out, 0, sizeof(float), stream);

    bt_partial_kernel<<<NBLK, NTHR, 0, stream>>>(
        (const float4*)e, (const float4*)tau, acc, B, nslot);
    bt_final_kernel<<<8, 64, 0, stream>>>(acc, (float*)d_out, B, nslot);
}